// Round 3
// baseline (401.338 us; speedup 1.0000x reference)
//
#include <hip/hip_runtime.h>

// out[b,i,o] = S[b,i,:]·W[o,:] + A[b,i]*bias[o]
//   S[b,i,d] = sum_j adj[b,i,j]*(text[b,j,d] + dep[b,j,i,d]),  A = sum_j adj
//
// Two-phase, j-major so the 268 MB dep stream is read CONTIGUOUSLY:
//   phase 1: block (b, jg, ic) reads dep[b, j, i0:i0+8, :] (8KB contiguous per j,
//            32 j's), folds text term (L1-hot row), accumulates in registers,
//            writes partial S_p[b][jg][i][d] (32 MB ws).
//   phase 2: block (b,i) reduces 8 partials + adj row-sum A + W epilogue.

#define LL  256
#define DD  256
#define D4  64    // DD/4
#define G   8     // j-groups
#define JPG 32    // j per group
#define ICL 8     // i per phase-1 block

__global__ __launch_bounds__(256) void tgc_phase1(
    const float* __restrict__ text,     // [B,L,D]
    const float* __restrict__ adj,      // [B,L,L]
    const float* __restrict__ dep,      // [B,L,L,D]
    float* __restrict__ sp)             // ws: [B][G][L][D] fp32 partials
{
    const int bid = blockIdx.x;         // ((b*G + jg)*32 + ic)
    const int ic  = bid & 31;
    const int jg  = (bid >> 5) & (G - 1);
    const int b   = bid >> 8;
    const int i0  = ic * ICL;
    const int j0  = jg * JPG;
    const int t   = threadIdx.x;
    const int w   = t >> 6;             // wave 0..3
    const int l   = t & 63;

    __shared__ float adjs[ICL][JPG];    // adj[b][i0+k][j0+jl]

    {
        const int k  = t >> 5;          // 0..7
        const int jl = t & 31;
        adjs[k][jl] = adj[((b * LL) + i0 + k) * LL + j0 + jl];
    }
    __syncthreads();

    const float4* __restrict__ dep4  = (const float4*)dep;
    const float4* __restrict__ text4 = (const float4*)text;

    // thread t owns (i_l=w, d4=l) and (i_l=4+w, d4=l); flat f = t and t+256
    float4 acc0 = make_float4(0.f, 0.f, 0.f, 0.f);
    float4 acc1 = make_float4(0.f, 0.f, 0.f, 0.f);

    const float4* dp = dep4 + ((size_t)(b * LL + j0) * LL + i0) * D4;
    const float4* tp = text4 + ((size_t)(b * LL + j0) * D4 + l);
    const size_t  JS = (size_t)LL * D4;   // +1 in j for dep (16384 float4)

    #pragma unroll 4
    for (int jl = 0; jl < JPG; ++jl) {
        const float  a0 = adjs[w][jl];
        const float  a1 = adjs[4 + w][jl];
        const float4 tv = tp[(size_t)jl * D4];          // text row: L1-hot
        const float4 d0 = dp[(size_t)jl * JS + t];       // 8KB contiguous/j
        const float4 d1 = dp[(size_t)jl * JS + t + 256];
        acc0.x += a0 * (tv.x + d0.x);
        acc0.y += a0 * (tv.y + d0.y);
        acc0.z += a0 * (tv.z + d0.z);
        acc0.w += a0 * (tv.w + d0.w);
        acc1.x += a1 * (tv.x + d1.x);
        acc1.y += a1 * (tv.y + d1.y);
        acc1.z += a1 * (tv.z + d1.z);
        acc1.w += a1 * (tv.w + d1.w);
    }

    float4* sp4 = (float4*)sp;
    const size_t base = ((size_t)(b * G + jg) * LL + i0) * D4;
    sp4[base + (size_t)(w)     * D4 + l] = acc0;   // i_l = w
    sp4[base + (size_t)(4 + w) * D4 + l] = acc1;   // i_l = 4+w
}

__global__ __launch_bounds__(256) void tgc_phase2(
    const float* __restrict__ adj,      // [B,L,L]
    const float* __restrict__ sp,       // [B][G][L][D]
    const float* __restrict__ W,        // [Do,Di]
    const float* __restrict__ bias,     // [Do]
    float* __restrict__ out)            // [B,L,Do]
{
    const int bi = blockIdx.x;          // b*L + i
    const int b  = bi >> 8;
    const int i  = bi & 255;
    const int t  = threadIdx.x;
    const int w  = t >> 6;
    const int l  = t & 63;

    __shared__ float4 red[4][64];
    __shared__ float  ared[4];
    __shared__ float4 sfin[64];

    // A = sum_j adj[b,i,j]: each wave reduces its 64
    float av = adj[bi * LL + t];
    #pragma unroll
    for (int off = 32; off > 0; off >>= 1) av += __shfl_down(av, off);
    if (l == 0) ared[w] = av;

    // sum partials: wave w takes jg = w and w+4
    const float4* sp4 = (const float4*)sp;
    const float4  s0 = sp4[((size_t)(b * G + w)     * LL + i) * D4 + l];
    const float4  s1 = sp4[((size_t)(b * G + 4 + w) * LL + i) * D4 + l];
    red[w][l] = make_float4(s0.x + s1.x, s0.y + s1.y, s0.z + s1.z, s0.w + s1.w);
    __syncthreads();

    if (w == 0) {
        const float4 r0 = red[0][l], r1 = red[1][l], r2 = red[2][l], r3 = red[3][l];
        sfin[l] = make_float4(r0.x + r1.x + r2.x + r3.x,
                              r0.y + r1.y + r2.y + r3.y,
                              r0.z + r1.z + r2.z + r3.z,
                              r0.w + r1.w + r2.w + r3.w);
    }
    __syncthreads();

    const float A = ared[0] + ared[1] + ared[2] + ared[3];

    // epilogue: thread t = output column o; W rows L2-resident
    const float4* W4 = (const float4*)W;
    float oacc = 0.f;
    #pragma unroll 8
    for (int d4 = 0; d4 < D4; ++d4) {
        const float4 s  = sfin[d4];
        const float4 wv = W4[t * D4 + d4];
        oacc += s.x * wv.x + s.y * wv.y + s.z * wv.z + s.w * wv.w;
    }
    out[bi * DD + t] = oacc + A * bias[t];
}

extern "C" void kernel_launch(void* const* d_in, const int* in_sizes, int n_in,
                              void* d_out, int out_size, void* d_ws, size_t ws_size,
                              hipStream_t stream) {
    const float* text = (const float*)d_in[0];
    const float* adj  = (const float*)d_in[1];
    const float* dep  = (const float*)d_in[2];
    const float* W    = (const float*)d_in[3];
    const float* bias = (const float*)d_in[4];
    float* out = (float*)d_out;
    float* sp  = (float*)d_ws;          // 4*8*256*256*4 = 32 MB

    tgc_phase1<<<dim3(4 * G * 32), dim3(256), 0, stream>>>(text, adj, dep, sp);
    tgc_phase2<<<dim3(4 * LL), dim3(256), 0, stream>>>(adj, sp, W, bias, out);
}

// Round 5
// 377.161 us; speedup vs baseline: 1.0641x; 1.0641x over previous
//
#include <hip/hip_runtime.h>

// out[b,i,o] = S[b,i,:]·W[o,:] + A[b,i]*bias[o]
//   S[b,i,d] = sum_j adj[b,i,j]*(text[b,j,d] + dep[b,j,i,d]),  A = sum_j adj
//
// Discriminator round: max occupancy on the dep stream.
//   phase 1: 2048 blocks = (b,i,j-half); 8 blocks/CU = 32 waves/CU (full).
//            Pure dep stream (nontemporal) + text term from L2.
//            Partial S halves -> ws (2 MB only).
//   phase 2: 1024 blocks = (b,i): sum 2 halves + adj row-sum A + W epilogue.

#define LL 256
#define DD 256
#define D4 64   // DD/4

// native clang vector type — __builtin_nontemporal_load needs this, not
// HIP_vector_type
typedef float float4n __attribute__((ext_vector_type(4)));

__global__ __launch_bounds__(256, 8) void tgc_phase1(
    const float* __restrict__ text,     // [B,L,D]
    const float* __restrict__ adj,      // [B,L,L]
    const float* __restrict__ dep,      // [B,L,L,D]
    float4* __restrict__ spS)           // ws: [2048][64] float4 partial S
{
    const int bid = blockIdx.x;         // (bi<<1) | jh
    const int jh  = bid & 1;
    const int bi  = bid >> 1;
    const int b   = bi >> 8;
    const int i   = bi & 255;
    const int t   = threadIdx.x;
    const int g   = t >> 6;             // j-group 0..3 within half
    const int l   = t & 63;             // d4 = l

    __shared__ float  adjs[128];
    __shared__ float4 red[4][64];

    if (t < 128) adjs[t] = adj[bi * LL + jh * 128 + t];
    __syncthreads();

    const float4n* __restrict__ dep4 = (const float4n*)dep;
    const float4*  __restrict__ text4 = (const float4*)text;

    float4 acc = make_float4(0.f, 0.f, 0.f, 0.f);

    // dep stream: j = jh*128 + 4*jj + g, jj = 0..31 (nontemporal: zero reuse)
    {
        const float4n* dp = dep4 + (((size_t)(b * LL + jh * 128 + g) * LL + i) * D4 + l);
        const size_t   JS = (size_t)4 * LL * D4;
        #pragma unroll 4
        for (int jj = 0; jj < 32; ++jj) {
            const float   a = adjs[(jj << 2) + g];
            const float4n d = __builtin_nontemporal_load(dp);
            acc.x += a * d.x;
            acc.y += a * d.y;
            acc.z += a * d.z;
            acc.w += a * d.w;
            dp += JS;
        }
    }
    // text term for the same j's (L2-resident, 1 MB total)
    {
        const float4* tp = text4 + ((size_t)(b * LL + jh * 128 + g) * D4 + l);
        const size_t  TS = (size_t)4 * D4;
        #pragma unroll 4
        for (int jj = 0; jj < 32; ++jj) {
            const float  a  = adjs[(jj << 2) + g];
            const float4 tv = *tp;
            acc.x += a * tv.x;
            acc.y += a * tv.y;
            acc.z += a * tv.z;
            acc.w += a * tv.w;
            tp += TS;
        }
    }

    red[g][l] = acc;
    __syncthreads();
    if (g == 0) {
        const float4 r0 = red[0][l], r1 = red[1][l], r2 = red[2][l], r3 = red[3][l];
        spS[(size_t)bid * 64 + l] = make_float4(r0.x + r1.x + r2.x + r3.x,
                                                r0.y + r1.y + r2.y + r3.y,
                                                r0.z + r1.z + r2.z + r3.z,
                                                r0.w + r1.w + r2.w + r3.w);
    }
}

__global__ __launch_bounds__(256) void tgc_phase2(
    const float* __restrict__ adj,      // [B,L,L]
    const float4* __restrict__ spS,     // [2048][64]
    const float* __restrict__ W,        // [Do,Di]
    const float* __restrict__ bias,     // [Do]
    float* __restrict__ out)            // [B,L,Do]
{
    const int bi = blockIdx.x;
    const int t  = threadIdx.x;
    const int w  = t >> 6;
    const int l  = t & 63;

    __shared__ float4 sfin[64];
    __shared__ float  ared[4];

    // A = sum_j adj[b,i,j]
    float av = adj[bi * LL + t];
    #pragma unroll
    for (int off = 32; off > 0; off >>= 1) av += __shfl_down(av, off);
    if (l == 0) ared[w] = av;

    // S = half0 + half1
    if (w == 0) {
        const float4 s0 = spS[(size_t)(bi * 2)     * 64 + l];
        const float4 s1 = spS[(size_t)(bi * 2 + 1) * 64 + l];
        sfin[l] = make_float4(s0.x + s1.x, s0.y + s1.y, s0.z + s1.z, s0.w + s1.w);
    }
    __syncthreads();

    const float A = ared[0] + ared[1] + ared[2] + ared[3];

    // thread t = output column o
    const float4* W4 = (const float4*)W;
    float oacc = 0.f;
    #pragma unroll 8
    for (int d4 = 0; d4 < D4; ++d4) {
        const float4 s  = sfin[d4];
        const float4 wv = W4[t * D4 + d4];
        oacc += s.x * wv.x + s.y * wv.y + s.z * wv.z + s.w * wv.w;
    }
    out[bi * DD + t] = oacc + A * bias[t];
}

extern "C" void kernel_launch(void* const* d_in, const int* in_sizes, int n_in,
                              void* d_out, int out_size, void* d_ws, size_t ws_size,
                              hipStream_t stream) {
    const float* text = (const float*)d_in[0];
    const float* adj  = (const float*)d_in[1];
    const float* dep  = (const float*)d_in[2];
    const float* W    = (const float*)d_in[3];
    const float* bias = (const float*)d_in[4];
    float* out = (float*)d_out;
    float4* spS = (float4*)d_ws;        // 2048*64*16 = 2 MB

    tgc_phase1<<<dim3(2048), dim3(256), 0, stream>>>(text, adj, dep, spS);
    tgc_phase2<<<dim3(1024), dim3(256), 0, stream>>>(adj, spS, W, bias, out);
}